// Round 6
// baseline (3205.439 us; speedup 1.0000x reference)
//
#include <hip/hip_runtime.h>

typedef float f32x4 __attribute__((ext_vector_type(4)));
typedef short s16x8 __attribute__((ext_vector_type(8)));
typedef unsigned short u16;

#define NST    2048
#define KDIM   2112
#define NYD    128
#define NUD    64
#define BD     256
#define NSTEP  80

__device__ __forceinline__ u16 f2bf(float f) {
  unsigned int u = __builtin_bit_cast(unsigned int, f);
  u = (u + 0x7FFFu + ((u >> 16) & 1u)) >> 16;
  return (u16)u;
}

__device__ __forceinline__ float tanh_fast(float x) {
  float ax = __builtin_fabsf(x);
  float e  = __expf(-2.0f * ax);
  float r  = (1.0f - e) / (1.0f + e);
  return __builtin_copysignf(r, x);
}

__device__ __forceinline__ f32x4 MF(s16x8 a, s16x8 b, f32x4 c) {
  return __builtin_amdgcn_mfma_f32_16x16x32_bf16(a, b, c, 0, 0, 0);
}

// Spin until *p >= v, then acquire-fence (agent). The fence also pins
// subsequent non-atomic stores below the wait (WAR correctness).
__device__ __forceinline__ void waitge(int* p, int v) {
  int g = 0;
  while (__hip_atomic_load(p, __ATOMIC_RELAXED, __HIP_MEMORY_SCOPE_AGENT) < v) {
    __builtin_amdgcn_s_sleep(2);
    if (++g > (1 << 24)) break;
  }
  __builtin_amdgcn_fence(__ATOMIC_ACQUIRE, "agent");
}

// flags: rdycnt [0,128) 8 counters stride16 init 16; pseq [2048,4096);
//        consumed [4096,6144); xdone [6144,7424).
__global__ void k_init(int* flags) {
  int i = blockIdx.x * 256 + threadIdx.x;
  if (i < 7424) flags[i] = (i < 128 && (i & 15) == 0) ? 16 : 0;
}

// A[2112][2048] f32 -> At[2048][2112] bf16 (At[n][k] = A[k][n])
__global__ void k_prepA(const float* __restrict__ A, u16* __restrict__ At) {
  __shared__ float tile[64][65];
  int nbase = blockIdx.x * 64;
  int kbase = blockIdx.y * 64;
  int tx = threadIdx.x & 63;
  int ty = threadIdx.x >> 6;
  for (int r = 0; r < 64; r += 4)
    tile[r + ty][tx] = A[(size_t)(kbase + r + ty) * NST + nbase + tx];
  __syncthreads();
  for (int r = 0; r < 64; r += 4) {
    int ni = r + ty;
    At[(size_t)(nbase + ni) * KDIM + kbase + tx] = f2bf(tile[tx][ni]);
  }
}

// X ring slot 1 = full X_0 row (state teacher-forced + U[0] tail); out[0] = err0
__global__ void k_prepX0(const float* __restrict__ U, const float* __restrict__ Y,
                         const float* __restrict__ init, u16* __restrict__ X1,
                         float* __restrict__ out) {
  int m = blockIdx.x;
  int c = blockIdx.y * 256 + threadIdx.x;
  if (c >= KDIM) return;
  float v;
  if (c < NYD) {
    float y = Y[(size_t)m * NYD + c];
    out[(size_t)m * NYD + c] = init[c] - y;
    v = y;
  } else if (c < NST) {
    v = init[c];
  } else {
    v = U[(size_t)m * NUD + (c - NST)];  // U[0]
  }
  X1[(size_t)m * KDIM + c] = f2bf(tanh_fast(v));
}

// Xu[t][m][u] = tanh(U[t][m][u])
__global__ void k_prepXu(const float* __restrict__ U, u16* __restrict__ Xu) {
  int i = blockIdx.x * 256 + threadIdx.x;
  if (i < NSTEP * BD * NUD) Xu[i] = f2bf(tanh_fast(U[i]));
}

template<int N>
__device__ __forceinline__ void gemm_loop(const u16* __restrict__ x0,
                                          const u16* __restrict__ x1,
                                          const u16* __restrict__ bb,
                                          f32x4& a00, f32x4& a01,
                                          f32x4& a10, f32x4& a11) {
#pragma unroll 4
  for (int kc = 0; kc < N; ++kc) {
    s16x8 A0 = *(const s16x8*)(x0 + (size_t)kc * 32);
    s16x8 A1 = *(const s16x8*)(x1 + (size_t)kc * 32);
    s16x8 B0 = *(const s16x8*)(bb + (size_t)kc * 2048);
    s16x8 B1 = *(const s16x8*)(bb + (size_t)kc * 2048 + 512);
    a00 = MF(A0, B0, a00); a01 = MF(A0, B1, a01);
    a10 = MF(A1, B0, a10); a11 = MF(A1, B1, a11);
  }
}

// ---- persistent kernel: 79 steps. 256 WGs = 32 j (64 cols) x 2 ks x 4 mb (64 rows).
// j&7 == w&7 so owner (ks0) / partner (ks1) of a tile share an XCD.
// B slice (64 cols x K-half) lives in LDS for the whole kernel; X frags are plain
// cached global loads (freshness via acquire fences inside waitge).
__global__ void __launch_bounds__(256, 1)
k_persist(const u16* __restrict__ At, u16* __restrict__ Xr0, u16* __restrict__ Xr1,
          u16* __restrict__ Xr2, const u16* __restrict__ Xu,
          float* __restrict__ partial, int* rdycnt, int* pseq, int* consumed,
          int* xdone, const float* __restrict__ Y, float* __restrict__ out) {
  extern __shared__ u16 Blds[];   // [NKC][4 frags][64 lanes][8] : <= 139,264 B

  const int w = blockIdx.x;
  const int j  = ((w >> 3) & 3) * 8 + (w & 7);  // 0..31, j&7 == XCD
  const int ks = (w >> 5) & 1;
  const int mb = (w >> 6) & 3;
  const int tid = threadIdx.x, wv = tid >> 6, lane = tid & 63;
  const int l15 = lane & 15, lg = lane >> 4;
  const int wr = wv >> 1, wc = wv & 1;          // wave = 32 rows x 32 cols
  const int m0 = mb * 64, n0 = j * 64;
  const int k0 = ks ? 1024 : 0;
  const int NKC = ks ? 34 : 32;                 // K-half: 1024 / 1088 (incl. U-tail)
  const int fidx = j * 4 + mb;
  const int rdy = (mb * 2 + ks) * 16;
  const int rel = (mb * 2 + (j >> 4)) * 16;

  // ---- B preload into LDS, frag-major: frag(kc,c16) at (kc*4+c16)*512 + lane*8
  {
    const int c16 = tid >> 6, bl15 = tid & 15, blg = (tid >> 4) & 3;
    const u16* src = At + (size_t)(n0 + c16 * 16 + bl15) * KDIM + k0 + blg * 8;
    u16* dst = Blds + ((size_t)c16 * 64 + blg * 16 + bl15) * 8;
    for (int kc = 0; kc < NKC; ++kc)
      *(s16x8*)(dst + (size_t)kc * 2048) = *(const s16x8*)(src + (size_t)kc * 32);
  }
  __syncthreads();

  const u16* bb = Blds + (size_t)(wc * 2) * 512 + (size_t)lane * 8;

  for (int tau = 1; tau < NSTEP; ++tau) {
    int rs = tau % 3, nsl = (tau + 1) % 3;
    const u16* xsrc = rs == 0 ? Xr0 : rs == 1 ? Xr1 : Xr2;
    u16* xdst = nsl == 0 ? Xr0 : nsl == 1 ? Xr1 : Xr2;

    // RAW: the 16 producers of this K-half finished step tau-1 (acquire inside)
    waitge(&rdycnt[rdy], 16 * tau);

    f32x4 acc00 = {0.f,0.f,0.f,0.f}, acc01 = {0.f,0.f,0.f,0.f};
    f32x4 acc10 = {0.f,0.f,0.f,0.f}, acc11 = {0.f,0.f,0.f,0.f};

    const u16* x0 = xsrc + (size_t)(m0 + wr * 32 + l15) * KDIM + k0 + lg * 8;
    const u16* x1 = x0 + (size_t)16 * KDIM;
    if (ks) gemm_loop<34>(x0, x1, bb, acc00, acc01, acc10, acc11);
    else    gemm_loop<32>(x0, x1, bb, acc00, acc01, acc10, acc11);

    __syncthreads();   // all waves' X reads complete
    if (tid == 0)
      __hip_atomic_fetch_add(&xdone[tau * 16], 1, __ATOMIC_RELAXED,
                             __HIP_MEMORY_SCOPE_AGENT);

    if (ks) {
      // partner: WAR on parity slot (owner consumed step tau-2), then publish
      waitge(&consumed[fidx * 16], tau - 2);
      float* pb = partial + ((size_t)fidx * 2 + (tau & 1)) * 4096 + (size_t)tid * 16;
      *(f32x4*)(pb + 0)  = acc00;
      *(f32x4*)(pb + 4)  = acc01;
      *(f32x4*)(pb + 8)  = acc10;
      *(f32x4*)(pb + 12) = acc11;
      __syncthreads();
      if (tid == 0) {
        __builtin_amdgcn_fence(__ATOMIC_RELEASE, "agent");
        __hip_atomic_store(&pseq[fidx * 16], tau, __ATOMIC_RELAXED,
                           __HIP_MEMORY_SCOPE_AGENT);
      }
    } else {
      // owner: merge partner partial
      waitge(&pseq[fidx * 16], tau);
      const float* pb = partial + ((size_t)fidx * 2 + (tau & 1)) * 4096 +
                        (size_t)tid * 16;
      acc00 += *(const f32x4*)(pb + 0);
      acc01 += *(const f32x4*)(pb + 4);
      acc10 += *(const f32x4*)(pb + 8);
      acc11 += *(const f32x4*)(pb + 12);
      __syncthreads();
      if (tid == 0) {
        __builtin_amdgcn_fence(__ATOMIC_RELEASE, "agent");
        __hip_atomic_store(&consumed[fidx * 16], tau, __ATOMIC_RELAXED,
                           __HIP_MEMORY_SCOPE_AGENT);
      }
      // WAR on X ring: step tau-2 readers of the slot we are about to write
      if (tau >= 3) waitge(&xdone[(tau - 2) * 16], 256);

      bool past = tau < 64;
#define EPI1(ACC, F, G) do {                                                  \
      _Pragma("unroll")                                                       \
      for (int r = 0; r < 4; ++r) {                                           \
        int m = m0 + wr * 32 + (F) * 16 + lg * 4 + r;                         \
        int col = n0 + wc * 32 + (G) * 16 + l15;                              \
        float v = ACC[r]; float xv;                                           \
        if (col < NYD) {                                                      \
          size_t oo = ((size_t)tau * BD + m) * NYD + col;                     \
          if (past) { float y = Y[oo]; out[oo] = v - y; xv = tanh_fast(y); }  \
          else      { out[oo] = v; xv = tanh_fast(v); }                       \
        } else xv = tanh_fast(v);                                             \
        xdst[(size_t)m * KDIM + col] = f2bf(xv);                              \
      }                                                                       \
    } while (0)
      EPI1(acc00, 0, 0); EPI1(acc01, 0, 1); EPI1(acc10, 1, 0); EPI1(acc11, 1, 1);
#undef EPI1
      // j==16 owner fills the U-tail of the ring slot: 64 rows x 64 cols = 4096
      // u16; 256 threads x 16 u16 each (r4/r5 bug: only 8 u16/thread -> cols
      // 2080..2112 stayed 0xAA poison, deterministic absmax 0.83).
      if (j == 16) {
        int rrow = tid >> 2, roff = (tid & 3) * 16;
        const u16* us = Xu + (size_t)tau * (BD * NUD) +
                        (size_t)(m0 + rrow) * NUD + roff;
        u16* dd = xdst + (size_t)(m0 + rrow) * KDIM + NST + roff;
        *(s16x8*)(dd + 0) = *(const s16x8*)(us + 0);
        *(s16x8*)(dd + 8) = *(const s16x8*)(us + 8);
      }
      __syncthreads();
      if (tid == 0) {
        __builtin_amdgcn_fence(__ATOMIC_RELEASE, "agent");
        __hip_atomic_fetch_add(&rdycnt[rel], 1, __ATOMIC_RELAXED,
                               __HIP_MEMORY_SCOPE_AGENT);
      }
    }
  }
}

extern "C" void kernel_launch(void* const* d_in, const int* in_sizes, int n_in,
                              void* d_out, int out_size, void* d_ws, size_t ws_size,
                              hipStream_t stream) {
  (void)in_sizes; (void)n_in; (void)out_size; (void)ws_size;
  const float* U    = (const float*)d_in[0];   // [80][256][64]
  const float* Y    = (const float*)d_in[1];   // [64][256][128]
  const float* A    = (const float*)d_in[2];   // [2112][2048]
  const float* init = (const float*)d_in[3];   // [1][2048]
  float* out = (float*)d_out;                  // [80][256][128]

  char* ws = (char*)d_ws;
  int* flags    = (int*)ws;
  int* rdycnt   = flags;
  int* pseq     = flags + 2048;
  int* consumed = flags + 4096;
  int* xdone    = flags + 6144;
  u16* At  = (u16*)(ws + 32768);               //  8,650,752 B
  u16* Xr0 = (u16*)(ws + 8683520);             //  1,081,344 B
  u16* Xr1 = (u16*)(ws + 9764864);             //  1,081,344 B
  u16* Xr2 = (u16*)(ws + 10846208);            //  1,081,344 B
  u16* Xu  = (u16*)(ws + 11927552);            //  2,621,440 B
  float* partial = (float*)(ws + 14548992);    //  4,194,304 B  (total ~18.7 MB)

  k_init<<<29, 256, 0, stream>>>(flags);
  k_prepA<<<dim3(32, 33), 256, 0, stream>>>(A, At);
  k_prepX0<<<dim3(256, 9), 256, 0, stream>>>(U, Y, init, Xr1, out);
  k_prepXu<<<(NSTEP * BD * NUD + 255) / 256, 256, 0, stream>>>(U, Xu);

  // dynamic LDS 139,264 B (B slice, 34 chunks max) -> 1 WG/CU, all 256 co-resident.
  k_persist<<<256, 256, 139264, stream>>>(At, Xr0, Xr1, Xr2, Xu, partial,
                                          rdycnt, pseq, consumed, xdone, Y, out);
}

// Round 7
// 2437.619 us; speedup vs baseline: 1.3150x; 1.3150x over previous
//
#include <hip/hip_runtime.h>

typedef float f32x4 __attribute__((ext_vector_type(4)));
typedef short s16x8 __attribute__((ext_vector_type(8)));
typedef unsigned short u16;

#define NST    2048
#define KDIM   2112
#define NYD    128
#define NUD    64
#define BD     256
#define NSTEP  80

__device__ __forceinline__ u16 f2bf(float f) {
  unsigned int u = __builtin_bit_cast(unsigned int, f);
  u = (u + 0x7FFFu + ((u >> 16) & 1u)) >> 16;
  return (u16)u;
}

__device__ __forceinline__ float tanh_fast(float x) {
  float ax = __builtin_fabsf(x);
  float e  = __expf(-2.0f * ax);
  float r  = (1.0f - e) / (1.0f + e);
  return __builtin_copysignf(r, x);
}

__device__ __forceinline__ f32x4 MF(s16x8 a, s16x8 b, f32x4 c) {
  return __builtin_amdgcn_mfma_f32_16x16x32_bf16(a, b, c, 0, 0, 0);
}

// Spin until *p >= v. Compiler barrier only: the communicated data is accessed
// via volatile (sc0 sc1 = device-coherent, reads/writes the coherence point),
// so NO cache maintenance (wbl2/inv) is needed — that was r6's 40us/step cost.
// The asm memory clobber pins volatile accesses below the wait.
__device__ __forceinline__ void waitge(int* p, int v) {
  int g = 0;
  while (__hip_atomic_load(p, __ATOMIC_RELAXED, __HIP_MEMORY_SCOPE_AGENT) < v) {
    __builtin_amdgcn_s_sleep(2);
    if (++g > (1 << 24)) break;
  }
  asm volatile("" ::: "memory");
}

// flags: rdycnt [0,128) 8 counters stride16 init 16; pseq [2048,4096);
//        consumed [4096,6144); xdone [6144,7424).
__global__ void k_init(int* flags) {
  int i = blockIdx.x * 256 + threadIdx.x;
  if (i < 7424) flags[i] = (i < 128 && (i & 15) == 0) ? 16 : 0;
}

// A[2112][2048] f32 -> At[2048][2112] bf16 (At[n][k] = A[k][n])
__global__ void k_prepA(const float* __restrict__ A, u16* __restrict__ At) {
  __shared__ float tile[64][65];
  int nbase = blockIdx.x * 64;
  int kbase = blockIdx.y * 64;
  int tx = threadIdx.x & 63;
  int ty = threadIdx.x >> 6;
  for (int r = 0; r < 64; r += 4)
    tile[r + ty][tx] = A[(size_t)(kbase + r + ty) * NST + nbase + tx];
  __syncthreads();
  for (int r = 0; r < 64; r += 4) {
    int ni = r + ty;
    At[(size_t)(nbase + ni) * KDIM + kbase + tx] = f2bf(tile[tx][ni]);
  }
}

// X ring slot 1 = full X_0 row (state teacher-forced + U[0] tail); out[0] = err0
__global__ void k_prepX0(const float* __restrict__ U, const float* __restrict__ Y,
                         const float* __restrict__ init, u16* __restrict__ X1,
                         float* __restrict__ out) {
  int m = blockIdx.x;
  int c = blockIdx.y * 256 + threadIdx.x;
  if (c >= KDIM) return;
  float v;
  if (c < NYD) {
    float y = Y[(size_t)m * NYD + c];
    out[(size_t)m * NYD + c] = init[c] - y;
    v = y;
  } else if (c < NST) {
    v = init[c];
  } else {
    v = U[(size_t)m * NUD + (c - NST)];  // U[0]
  }
  X1[(size_t)m * KDIM + c] = f2bf(tanh_fast(v));
}

// Xu[t][m][u] = tanh(U[t][m][u])
__global__ void k_prepXu(const float* __restrict__ U, u16* __restrict__ Xu) {
  int i = blockIdx.x * 256 + threadIdx.x;
  if (i < NSTEP * BD * NUD) Xu[i] = f2bf(tanh_fast(U[i]));
}

template<int N>
__device__ __forceinline__ void gemm_loop(const u16* __restrict__ x0,
                                          const u16* __restrict__ x1,
                                          const u16* __restrict__ bb,
                                          f32x4& a00, f32x4& a01,
                                          f32x4& a10, f32x4& a11) {
#pragma unroll 4
  for (int kc = 0; kc < N; ++kc) {
    // volatile = sc0 sc1: device-coherent load (bypasses possibly-stale L1/L2)
    s16x8 A0 = *(const volatile s16x8*)(x0 + (size_t)kc * 32);
    s16x8 A1 = *(const volatile s16x8*)(x1 + (size_t)kc * 32);
    s16x8 B0 = *(const s16x8*)(bb + (size_t)kc * 2048);
    s16x8 B1 = *(const s16x8*)(bb + (size_t)kc * 2048 + 512);
    a00 = MF(A0, B0, a00); a01 = MF(A0, B1, a01);
    a10 = MF(A1, B0, a10); a11 = MF(A1, B1, a11);
  }
}

// ---- persistent kernel: 79 steps. 256 WGs = 32 j (64 cols) x 2 ks x 4 mb (64 rows).
// j&7 == w&7 so owner (ks0) / partner (ks1) of a tile share an XCD.
// B slice in LDS for the whole kernel. All cross-WG data (X ring, partials) is
// accessed volatile (device-coherent via IF$); flags are agent-scope atomics;
// __syncthreads' vmcnt-drain before the flag store provides release ordering.
__global__ void __launch_bounds__(256, 1)
k_persist(const u16* __restrict__ At, u16* __restrict__ Xr0, u16* __restrict__ Xr1,
          u16* __restrict__ Xr2, const u16* __restrict__ Xu,
          float* __restrict__ partial, int* rdycnt, int* pseq, int* consumed,
          int* xdone, const float* __restrict__ Y, float* __restrict__ out) {
  extern __shared__ u16 Blds[];   // [NKC][4 frags][64 lanes][8] : <= 139,264 B

  const int w = blockIdx.x;
  const int j  = ((w >> 3) & 3) * 8 + (w & 7);  // 0..31, j&7 == XCD
  const int ks = (w >> 5) & 1;
  const int mb = (w >> 6) & 3;
  const int tid = threadIdx.x, wv = tid >> 6, lane = tid & 63;
  const int l15 = lane & 15, lg = lane >> 4;
  const int wr = wv >> 1, wc = wv & 1;          // wave = 32 rows x 32 cols
  const int m0 = mb * 64, n0 = j * 64;
  const int k0 = ks ? 1024 : 0;
  const int NKC = ks ? 34 : 32;                 // K-half: 1024 / 1088 (incl. U-tail)
  const int fidx = j * 4 + mb;
  const int rdy = (mb * 2 + ks) * 16;
  const int rel = (mb * 2 + (j >> 4)) * 16;

  // ---- B preload into LDS, frag-major: frag(kc,c16) at (kc*4+c16)*512 + lane*8
  {
    const int c16 = tid >> 6, bl15 = tid & 15, blg = (tid >> 4) & 3;
    const u16* src = At + (size_t)(n0 + c16 * 16 + bl15) * KDIM + k0 + blg * 8;
    u16* dst = Blds + ((size_t)c16 * 64 + blg * 16 + bl15) * 8;
    for (int kc = 0; kc < NKC; ++kc)
      *(s16x8*)(dst + (size_t)kc * 2048) = *(const s16x8*)(src + (size_t)kc * 32);
  }
  __syncthreads();

  const u16* bb = Blds + (size_t)(wc * 2) * 512 + (size_t)lane * 8;

  for (int tau = 1; tau < NSTEP; ++tau) {
    int rs = tau % 3, nsl = (tau + 1) % 3;
    const u16* xsrc = rs == 0 ? Xr0 : rs == 1 ? Xr1 : Xr2;
    u16* xdst = nsl == 0 ? Xr0 : nsl == 1 ? Xr1 : Xr2;

    // RAW: the 16 producers of this K-half finished step tau-1
    waitge(&rdycnt[rdy], 16 * tau);

    f32x4 acc00 = {0.f,0.f,0.f,0.f}, acc01 = {0.f,0.f,0.f,0.f};
    f32x4 acc10 = {0.f,0.f,0.f,0.f}, acc11 = {0.f,0.f,0.f,0.f};

    const u16* x0 = xsrc + (size_t)(m0 + wr * 32 + l15) * KDIM + k0 + lg * 8;
    const u16* x1 = x0 + (size_t)16 * KDIM;
    if (ks) gemm_loop<34>(x0, x1, bb, acc00, acc01, acc10, acc11);
    else    gemm_loop<32>(x0, x1, bb, acc00, acc01, acc10, acc11);

    __syncthreads();   // all waves' X reads retired (barrier drains vmcnt)
    if (tid == 0)
      __hip_atomic_fetch_add(&xdone[tau * 16], 1, __ATOMIC_RELAXED,
                             __HIP_MEMORY_SCOPE_AGENT);

    if (ks) {
      // partner: WAR on parity slot (owner consumed step tau-2), then publish
      waitge(&consumed[fidx * 16], tau - 2);
      float* pb = partial + ((size_t)fidx * 2 + (tau & 1)) * 4096 + (size_t)tid * 16;
      *(volatile f32x4*)(pb + 0)  = acc00;
      *(volatile f32x4*)(pb + 4)  = acc01;
      *(volatile f32x4*)(pb + 8)  = acc10;
      *(volatile f32x4*)(pb + 12) = acc11;
      __syncthreads();   // vmcnt(0): coherent stores at coherence point
      if (tid == 0)
        __hip_atomic_store(&pseq[fidx * 16], tau, __ATOMIC_RELAXED,
                           __HIP_MEMORY_SCOPE_AGENT);
    } else {
      // owner: merge partner partial
      waitge(&pseq[fidx * 16], tau);
      const float* pb = partial + ((size_t)fidx * 2 + (tau & 1)) * 4096 +
                        (size_t)tid * 16;
      f32x4 p0 = *(const volatile f32x4*)(pb + 0);
      f32x4 p1 = *(const volatile f32x4*)(pb + 4);
      f32x4 p2 = *(const volatile f32x4*)(pb + 8);
      f32x4 p3 = *(const volatile f32x4*)(pb + 12);
      acc00 += p0; acc01 += p1; acc10 += p2; acc11 += p3;
      __syncthreads();   // all threads' partial loads complete
      if (tid == 0)
        __hip_atomic_store(&consumed[fidx * 16], tau, __ATOMIC_RELAXED,
                           __HIP_MEMORY_SCOPE_AGENT);
      // WAR on X ring: step tau-2 readers of the slot we are about to write
      if (tau >= 3) waitge(&xdone[(tau - 2) * 16], 256);

      bool past = tau < 64;
#define EPI1(ACC, F, G) do {                                                  \
      _Pragma("unroll")                                                       \
      for (int r = 0; r < 4; ++r) {                                           \
        int m = m0 + wr * 32 + (F) * 16 + lg * 4 + r;                         \
        int col = n0 + wc * 32 + (G) * 16 + l15;                              \
        float v = ACC[r]; float xv;                                           \
        if (col < NYD) {                                                      \
          size_t oo = ((size_t)tau * BD + m) * NYD + col;                     \
          if (past) { float y = Y[oo]; out[oo] = v - y; xv = tanh_fast(y); }  \
          else      { out[oo] = v; xv = tanh_fast(v); }                       \
        } else xv = tanh_fast(v);                                             \
        *(volatile u16*)(xdst + (size_t)m * KDIM + col) = f2bf(xv);           \
      }                                                                       \
    } while (0)
      EPI1(acc00, 0, 0); EPI1(acc01, 0, 1); EPI1(acc10, 1, 0); EPI1(acc11, 1, 1);
#undef EPI1
      // j==16 owner fills the U-tail of the ring slot: 64 rows x 64 cols =
      // 4096 u16; 256 threads x 16 u16 each.
      if (j == 16) {
        int rrow = tid >> 2, roff = (tid & 3) * 16;
        const u16* us = Xu + (size_t)tau * (BD * NUD) +
                        (size_t)(m0 + rrow) * NUD + roff;
        u16* dd = xdst + (size_t)(m0 + rrow) * KDIM + NST + roff;
        *(volatile s16x8*)(dd + 0) = *(const s16x8*)(us + 0);
        *(volatile s16x8*)(dd + 8) = *(const s16x8*)(us + 8);
      }
      __syncthreads();   // vmcnt(0): X stores at coherence point
      if (tid == 0)
        __hip_atomic_fetch_add(&rdycnt[rel], 1, __ATOMIC_RELAXED,
                               __HIP_MEMORY_SCOPE_AGENT);
    }
  }
}

extern "C" void kernel_launch(void* const* d_in, const int* in_sizes, int n_in,
                              void* d_out, int out_size, void* d_ws, size_t ws_size,
                              hipStream_t stream) {
  (void)in_sizes; (void)n_in; (void)out_size; (void)ws_size;
  const float* U    = (const float*)d_in[0];   // [80][256][64]
  const float* Y    = (const float*)d_in[1];   // [64][256][128]
  const float* A    = (const float*)d_in[2];   // [2112][2048]
  const float* init = (const float*)d_in[3];   // [1][2048]
  float* out = (float*)d_out;                  // [80][256][128]

  char* ws = (char*)d_ws;
  int* flags    = (int*)ws;
  int* rdycnt   = flags;
  int* pseq     = flags + 2048;
  int* consumed = flags + 4096;
  int* xdone    = flags + 6144;
  u16* At  = (u16*)(ws + 32768);               //  8,650,752 B
  u16* Xr0 = (u16*)(ws + 8683520);             //  1,081,344 B
  u16* Xr1 = (u16*)(ws + 9764864);             //  1,081,344 B
  u16* Xr2 = (u16*)(ws + 10846208);            //  1,081,344 B
  u16* Xu  = (u16*)(ws + 11927552);            //  2,621,440 B
  float* partial = (float*)(ws + 14548992);    //  4,194,304 B  (total ~18.7 MB)

  k_init<<<29, 256, 0, stream>>>(flags);
  k_prepA<<<dim3(32, 33), 256, 0, stream>>>(A, At);
  k_prepX0<<<dim3(256, 9), 256, 0, stream>>>(U, Y, init, Xr1, out);
  k_prepXu<<<(NSTEP * BD * NUD + 255) / 256, 256, 0, stream>>>(U, Xu);

  // dynamic LDS 139,264 B (B slice, 34 chunks max) -> 1 WG/CU, all 256 co-resident.
  k_persist<<<256, 256, 139264, stream>>>(At, Xr0, Xr1, Xr2, Xu, partial,
                                          rdycnt, pseq, consumed, xdone, Y, out);
}